// Round 6
// baseline (713.114 us; speedup 1.0000x reference)
//
#include <hip/hip_runtime.h>
#include <hip/hip_fp16.h>

#define N_NODES_C 100000
#define N_EDGES_C 1600000
#define N_GRAPHS_C 2000
#define HID 128
#define BN_EPS_C 1e-5f
#define NBUCK 391          // ceil(100000 / 256) buckets of 256 nodes
#define PART_TILE 4096     // edges per block in hist/partition kernels

typedef _Float16 half8 __attribute__((ext_vector_type(8)));
typedef _Float16 half4v __attribute__((ext_vector_type(4)));
typedef float float4v __attribute__((ext_vector_type(4)));

// ---------------- CSR build: bucket partition (ebuf packed: src<<8 | dst&255) ----------------

__global__ __launch_bounds__(256) void kb_hist(const int* __restrict__ dst, int* __restrict__ bcount) {
    __shared__ int hist[NBUCK];
    const int t = threadIdx.x;
    for (int b = t; b < NBUCK; b += 256) hist[b] = 0;
    __syncthreads();
    const int e0 = blockIdx.x * PART_TILE;
    #pragma unroll
    for (int k = 0; k < 16; k++) {
        int e = e0 + k * 256 + t;
        if (e < N_EDGES_C) atomicAdd(&hist[dst[e] >> 8], 1);
    }
    __syncthreads();
    for (int b = t; b < NBUCK; b += 256) {
        int c = hist[b];
        if (c) atomicAdd(&bcount[b], c);
    }
}

__global__ __launch_bounds__(512) void kb_scan(const int* __restrict__ bcount,
                                               int* __restrict__ bbase, int* __restrict__ bcursor) {
    __shared__ int s[512];
    const int t = threadIdx.x;
    int v = (t < NBUCK) ? bcount[t] : 0;
    s[t] = v;
    __syncthreads();
    for (int off = 1; off < 512; off <<= 1) {
        int u = (t >= off) ? s[t - off] : 0;
        __syncthreads();
        s[t] += u;
        __syncthreads();
    }
    if (t < NBUCK) { int e = s[t] - v; bbase[t] = e; bcursor[t] = e; }
    if (t == 0) bbase[NBUCK] = N_EDGES_C;
}

__global__ __launch_bounds__(256) void kb_part(const int* __restrict__ src, const int* __restrict__ dst,
                                               int* __restrict__ bcursor, unsigned int* __restrict__ ebuf) {
    __shared__ int hist[NBUCK];
    __shared__ int startA[NBUCK];
    __shared__ int lcur[NBUCK];
    const int t = threadIdx.x;
    for (int b = t; b < NBUCK; b += 256) { hist[b] = 0; lcur[b] = 0; }
    __syncthreads();
    const int e0 = blockIdx.x * PART_TILE;
    #pragma unroll
    for (int k = 0; k < 16; k++) {
        int e = e0 + k * 256 + t;
        if (e < N_EDGES_C) atomicAdd(&hist[dst[e] >> 8], 1);
    }
    __syncthreads();
    for (int b = t; b < NBUCK; b += 256) {
        int c = hist[b];
        startA[b] = c ? atomicAdd(&bcursor[b], c) : 0;
    }
    __syncthreads();
    #pragma unroll
    for (int k = 0; k < 16; k++) {
        int e = e0 + k * 256 + t;
        if (e < N_EDGES_C) {
            int d = dst[e];
            int b = d >> 8;
            int pos = startA[b] + atomicAdd(&lcur[b], 1);
            ebuf[pos] = ((unsigned int)src[e] << 8) | (unsigned int)(d & 255);
        }
    }
}

// One block per bucket: local count+scan -> offs, norm, csr_src (all writes bucket-local).
__global__ __launch_bounds__(256) void kb_fill(const unsigned int* __restrict__ ebuf, const int* __restrict__ bbase,
                                               int* __restrict__ csr_src, int* __restrict__ offs,
                                               float* __restrict__ norm) {
    __shared__ int s[256];
    __shared__ int excl[256];
    __shared__ int lcur[256];
    const int b = blockIdx.x, t = threadIdx.x;
    const int base = b << 8;
    const int e0 = bbase[b], e1 = bbase[b + 1];
    s[t] = 0; lcur[t] = 0;
    __syncthreads();
    for (int e = e0 + t; e < e1; e += 256)
        atomicAdd(&s[ebuf[e] & 255u], 1);
    __syncthreads();
    int own = s[t];
    for (int off = 1; off < 256; off <<= 1) {
        int v = (t >= off) ? s[t - off] : 0;
        __syncthreads();
        s[t] += v;
        __syncthreads();
    }
    excl[t] = s[t] - own;
    int node = base + t;
    if (node < N_NODES_C) {
        offs[node] = e0 + (s[t] - own);
        norm[node] = rsqrtf((float)own + 1.0f);
    }
    if (b == 0 && t == 0) offs[N_NODES_C] = N_EDGES_C;
    __syncthreads();
    for (int e = e0 + t; e < e1; e += 256) {
        unsigned int p = ebuf[e];
        int l = p & 255u;
        int pos = e0 + excl[l] + atomicAdd(&lcur[l], 1);
        csr_src[pos] = (int)(p >> 8);
    }
}

// ---------------- precompute ----------------

// x -> fp16 pre-scaled by norm (x̂ = norm ⊙ x)
__global__ __launch_bounds__(256) void k_cast(const float* __restrict__ x, const float* __restrict__ norm,
                                              _Float16* __restrict__ xh) {
    long base = ((long)blockIdx.x * 256 + threadIdx.x) * 8;
    int row = (int)(base >> 7);
    float nv = norm[row];
    float4 a = *(const float4*)&x[base];
    float4 b = *(const float4*)&x[base + 4];
    _Float16 p[8] = {(_Float16)(a.x * nv), (_Float16)(a.y * nv), (_Float16)(a.z * nv), (_Float16)(a.w * nv),
                     (_Float16)(b.x * nv), (_Float16)(b.y * nv), (_Float16)(b.z * nv), (_Float16)(b.w * nv)};
    *(half8*)&xh[base] = *(half8*)p;
}

// W -> fp16 transposed [n][k]
__global__ __launch_bounds__(256) void k_tw(const float* __restrict__ Ws_all, _Float16* __restrict__ WT) {
    int idx = blockIdx.x * 256 + threadIdx.x;     // 4*128*128 = 65536
    int l = idx >> 14, r = idx & 16383, k = r >> 7, n = r & 127;
    WT[l * 16384 + n * HID + k] = (_Float16)Ws_all[idx];
}

// Fold bias+BN into per-channel scale/shift: out = z*A + B
__global__ __launch_bounds__(256) void k_bn(const float* __restrict__ bs, const float* __restrict__ mean,
                                            const float* __restrict__ gamma, const float* __restrict__ var,
                                            const float* __restrict__ beta,
                                            float* __restrict__ Asc, float* __restrict__ Bsh) {
    int i = blockIdx.x * 256 + threadIdx.x;       // 4*128 = 512
    if (i < 4 * HID) {
        float sc = gamma[i] * rsqrtf(var[i] + BN_EPS_C);
        Asc[i] = sc;
        Bsh[i] = (bs[i] - mean[i]) * sc + beta[i];
    }
}

// ---------------- Fused layer: gather(ĥ) -> LDS tile -> MFMA xW -> BN+ReLU -> ĥ_next ----------
// z_i = n_i (Σ_{s∈N(i)} ĥ_s + ĥ_i)   [self term inside parens is plain ĥ_i = n_i h_i,
//   since n_i² h_i = n_i · ĥ_i — round-5 bug was an extra n_i here]
// h_next = ReLU(z W * A + B);  store ĥ_next = n_i h_next (last layer stores plain h_next).
// Block: 256 thr / 4 waves; 128 nodes per block.

__global__ __launch_bounds__(256, 4) void k_layer(const _Float16* __restrict__ hin,
                                                  const _Float16* __restrict__ WT,
                                                  const int* __restrict__ offs, const int* __restrict__ csr_src,
                                                  const float* __restrict__ norm,
                                                  const float* __restrict__ Asc, const float* __restrict__ Bsh,
                                                  _Float16* __restrict__ hout, int scale_out) {
    __shared__ _Float16 g[128][136];   // gathered tile, padded pitch
    const int tid = threadIdx.x;
    const int wave = tid >> 6, lane = tid & 63;
    const int quad = lane >> 4, l16 = lane & 15;
    const int half = lane >> 5, cl = lane & 31;    // gather: half-wave per edge, 4 ch per lane
    const int nbase = blockIdx.x * 128;

    // W^T fragments for this wave's 32 output channels (A-operand of mfma)
    half8 Wf[2][4];
    #pragma unroll
    for (int c = 0; c < 2; c++)
        #pragma unroll
        for (int ks = 0; ks < 4; ks++)
            Wf[c][ks] = *(const half8*)&WT[((wave * 2 + c) * 16 + l16) * HID + ks * 32 + quad * 8];

    // ---- gather phase: this wave handles 32 nodes ----
    for (int t = 0; t < 32; t++) {
        const int local = wave * 32 + t;
        const int node = nbase + local;
        if (node < N_NODES_C) {
            float nv = norm[node];
            float acc[4] = {0.f, 0.f, 0.f, 0.f};
            if (half == 0) {   // self term inside parens: plain ĥ_i (NOT nv*ĥ_i)
                half4v sv = *(const half4v*)&hin[(long)node * HID + cl * 4];
                #pragma unroll
                for (int r = 0; r < 4; r++) acc[r] += (float)sv[r];
            }
            const int e0 = offs[node], e1 = offs[node + 1];
            int e = e0;
            for (; e + 8 <= e1; e += 8) {
                int s0 = csr_src[e + half];
                int s1 = csr_src[e + 2 + half];
                int s2 = csr_src[e + 4 + half];
                int s3 = csr_src[e + 6 + half];
                half4v v0 = *(const half4v*)&hin[(long)s0 * HID + cl * 4];
                half4v v1 = *(const half4v*)&hin[(long)s1 * HID + cl * 4];
                half4v v2 = *(const half4v*)&hin[(long)s2 * HID + cl * 4];
                half4v v3 = *(const half4v*)&hin[(long)s3 * HID + cl * 4];
                #pragma unroll
                for (int r = 0; r < 4; r++)
                    acc[r] += (float)v0[r] + (float)v1[r] + (float)v2[r] + (float)v3[r];
            }
            for (; e + 2 <= e1; e += 2) {
                int s = csr_src[e + half];
                half4v v = *(const half4v*)&hin[(long)s * HID + cl * 4];
                #pragma unroll
                for (int r = 0; r < 4; r++) acc[r] += (float)v[r];
            }
            if (e + half < e1) {
                int s = csr_src[e + half];
                half4v v = *(const half4v*)&hin[(long)s * HID + cl * 4];
                #pragma unroll
                for (int r = 0; r < 4; r++) acc[r] += (float)v[r];
            }
            #pragma unroll
            for (int r = 0; r < 4; r++) acc[r] += __shfl_xor(acc[r], 32);
            if (half == 0) {
                _Float16 p[4];
                #pragma unroll
                for (int r = 0; r < 4; r++) p[r] = (_Float16)(nv * acc[r]);
                *(ushort4*)&g[local][cl * 4] = *(ushort4*)p;
            }
        } else if (half == 0) {
            ushort4 z = make_ushort4(0, 0, 0, 0);
            *(ushort4*)&g[local][cl * 4] = z;
        }
    }
    __syncthreads();

    // ---- MFMA phase: z = g @ W for this wave's 32 channels, all 128 nodes ----
    float4 A0 = *(const float4*)&Asc[(wave * 2 + 0) * 16 + quad * 4];
    float4 A1 = *(const float4*)&Asc[(wave * 2 + 1) * 16 + quad * 4];
    float4 B0 = *(const float4*)&Bsh[(wave * 2 + 0) * 16 + quad * 4];
    float4 B1 = *(const float4*)&Bsh[(wave * 2 + 1) * 16 + quad * 4];
    #pragma unroll
    for (int t = 0; t < 8; t++) {
        half8 Bf[4];
        #pragma unroll
        for (int ks = 0; ks < 4; ks++)
            Bf[ks] = *(const half8*)&g[t * 16 + l16][ks * 32 + quad * 8];
        float4v a0 = {0.f, 0.f, 0.f, 0.f}, a1 = {0.f, 0.f, 0.f, 0.f};
        #pragma unroll
        for (int ks = 0; ks < 4; ks++) {
            a0 = __builtin_amdgcn_mfma_f32_16x16x32_f16(Wf[0][ks], Bf[ks], a0, 0, 0, 0);
            a1 = __builtin_amdgcn_mfma_f32_16x16x32_f16(Wf[1][ks], Bf[ks], a1, 0, 0, 0);
        }
        int node = nbase + t * 16 + l16;
        if (node < N_NODES_C) {
            float nv = scale_out ? norm[node] : 1.0f;
            _Float16 p0[4], p1[4];
            p0[0] = (_Float16)(fmaxf(a0[0] * A0.x + B0.x, 0.f) * nv);
            p0[1] = (_Float16)(fmaxf(a0[1] * A0.y + B0.y, 0.f) * nv);
            p0[2] = (_Float16)(fmaxf(a0[2] * A0.z + B0.z, 0.f) * nv);
            p0[3] = (_Float16)(fmaxf(a0[3] * A0.w + B0.w, 0.f) * nv);
            p1[0] = (_Float16)(fmaxf(a1[0] * A1.x + B1.x, 0.f) * nv);
            p1[1] = (_Float16)(fmaxf(a1[1] * A1.y + B1.y, 0.f) * nv);
            p1[2] = (_Float16)(fmaxf(a1[2] * A1.z + B1.z, 0.f) * nv);
            p1[3] = (_Float16)(fmaxf(a1[3] * A1.w + B1.w, 0.f) * nv);
            *(ushort4*)&hout[(long)node * HID + (wave * 2 + 0) * 16 + quad * 4] = *(ushort4*)p0;
            *(ushort4*)&hout[(long)node * HID + (wave * 2 + 1) * 16 + quad * 4] = *(ushort4*)p1;
        }
    }
}

// ---------------- Pooling (batch sorted -> run-length local accumulation) ----------------

__global__ __launch_bounds__(64) void k_pool(const __half* __restrict__ h, const int* __restrict__ batch,
                                             float* __restrict__ psum, int* __restrict__ pcount) {
    const int j = threadIdx.x;          // channel pair j -> channels 2j, 2j+1
    const int i0 = blockIdx.x * 128;
    const int iend = min(i0 + 128, N_NODES_C);
    if (i0 >= N_NODES_C) return;
    float acc0 = 0.f, acc1 = 0.f;
    int cur = batch[i0];
    int runStart = i0;
    for (int i = i0; i < iend; i++) {
        int gidx = batch[i];
        if (gidx != cur) {
            atomicAdd(&psum[(long)cur * HID + 2 * j], acc0);
            atomicAdd(&psum[(long)cur * HID + 2 * j + 1], acc1);
            if (j == 0) atomicAdd(&pcount[cur], i - runStart);
            acc0 = 0.f; acc1 = 0.f; cur = gidx; runStart = i;
        }
        float2 f = __half22float2(*(const __half2*)&h[(long)i * HID + 2 * j]);
        acc0 += f.x; acc1 += f.y;
    }
    atomicAdd(&psum[(long)cur * HID + 2 * j], acc0);
    atomicAdd(&psum[(long)cur * HID + 2 * j + 1], acc1);
    if (j == 0) atomicAdd(&pcount[cur], iend - runStart);
}

__global__ __launch_bounds__(128) void k_final(const float* __restrict__ psum, const int* __restrict__ pcount,
                                               const float* __restrict__ W_out, const float* __restrict__ b_out,
                                               float* __restrict__ out) {
    __shared__ float red[128][5];
    const int g = blockIdx.x, j = threadIdx.x;
    float cnt = fmaxf((float)pcount[g], 1.f);
    float p = psum[(long)g * HID + j] / cnt;
    #pragma unroll
    for (int o = 0; o < 5; o++) red[j][o] = p * W_out[j * 5 + o];
    __syncthreads();
    for (int off = 64; off >= 1; off >>= 1) {
        if (j < off) {
            #pragma unroll
            for (int o = 0; o < 5; o++) red[j][o] += red[j + off][o];
        }
        __syncthreads();
    }
    if (j < 5) out[g * 5 + j] = red[0][j] + b_out[j];
}

// ---------------- launch ----------------

extern "C" void kernel_launch(void* const* d_in, const int* in_sizes, int n_in,
                              void* d_out, int out_size, void* d_ws, size_t ws_size,
                              hipStream_t stream) {
    const float* x        = (const float*)d_in[0];
    const int*   eidx     = (const int*)d_in[1];
    const int*   src      = eidx;
    const int*   dst      = eidx + N_EDGES_C;
    const int*   batch    = (const int*)d_in[2];
    const float* Ws_all   = (const float*)d_in[3];
    const float* bs       = (const float*)d_in[4];
    const float* gammas   = (const float*)d_in[5];
    const float* betas    = (const float*)d_in[6];
    const float* run_mean = (const float*)d_in[7];
    const float* run_var  = (const float*)d_in[8];
    const float* W_out    = (const float*)d_in[9];
    const float* b_out    = (const float*)d_in[10];
    float* out = (float*)d_out;

    char* wp = (char*)d_ws;
    auto alloc = [&](size_t bytes) { char* p = wp; wp += (bytes + 255) & ~(size_t)255; return p; };
    _Float16* hA      = (_Float16*)alloc((size_t)N_NODES_C * HID * 2);  // x̂ / ping
    _Float16* hB      = (_Float16*)alloc((size_t)N_NODES_C * HID * 2);  // pong
    unsigned int* ebuf = (unsigned int*)hB;                             // alias: dead before layer 0 writes hB
    _Float16* WT      = (_Float16*)alloc((size_t)4 * HID * HID * 2);
    float*    Asc     = (float*)alloc((size_t)4 * HID * 4);
    float*    Bsh     = (float*)alloc((size_t)4 * HID * 4);
    int*      csr_src = (int*)alloc((size_t)N_EDGES_C * 4);
    int*      offs    = (int*)alloc((size_t)(N_NODES_C + 1) * 4);
    float*    norm    = (float*)alloc((size_t)N_NODES_C * 4);
    int*      bcount  = (int*)alloc((NBUCK + 1) * 4);
    int*      bbase   = (int*)alloc((NBUCK + 1) * 4);
    int*      bcursor = (int*)alloc((NBUCK + 1) * 4);
    float*    psum    = (float*)alloc((size_t)N_GRAPHS_C * HID * 4);
    int*      pcount  = (int*)alloc((size_t)N_GRAPHS_C * 4);

    hipMemsetAsync(bcount, 0, (NBUCK + 1) * 4, stream);
    hipMemsetAsync(psum,   0, (size_t)N_GRAPHS_C * HID * 4, stream);
    hipMemsetAsync(pcount, 0, (size_t)N_GRAPHS_C * 4, stream);

    const int PB = (N_EDGES_C + PART_TILE - 1) / PART_TILE;  // 391
    kb_hist<<<PB, 256, 0, stream>>>(dst, bcount);
    kb_scan<<<1, 512, 0, stream>>>(bcount, bbase, bcursor);
    kb_part<<<PB, 256, 0, stream>>>(src, dst, bcursor, ebuf);
    kb_fill<<<NBUCK, 256, 0, stream>>>(ebuf, bbase, csr_src, offs, norm);

    k_tw  <<<256, 256, 0, stream>>>(Ws_all, WT);
    k_bn  <<<2, 256, 0, stream>>>(bs, run_mean, gammas, run_var, betas, Asc, Bsh);
    k_cast<<<(N_NODES_C * HID) / 2048, 256, 0, stream>>>(x, norm, hA);

    const int LB = (N_NODES_C + 127) / 128;   // 782
    _Float16* bufs[2] = {hA, hB};
    for (int l = 0; l < 4; l++) {
        k_layer<<<LB, 256, 0, stream>>>(bufs[l & 1], WT + (size_t)l * HID * HID,
                                        offs, csr_src, norm,
                                        Asc + l * HID, Bsh + l * HID,
                                        bufs[(l + 1) & 1], (l < 3) ? 1 : 0);
    }
    k_pool <<<LB, 64, 0, stream>>>((const __half*)bufs[0], batch, psum, pcount);
    k_final<<<N_GRAPHS_C, 128, 0, stream>>>(psum, pcount, W_out, b_out, out);
}

// Round 7
// 568.922 us; speedup vs baseline: 1.2534x; 1.2534x over previous
//
#include <hip/hip_runtime.h>
#include <hip/hip_fp16.h>

#define N_NODES_C 100000
#define N_EDGES_C 1600000
#define N_GRAPHS_C 2000
#define HID 128
#define BN_EPS_C 1e-5f
#define NBUCK 391          // ceil(100000 / 256) buckets of 256 nodes
#define PART_TILE 4096     // edges per block in hist/partition kernels

typedef _Float16 half8 __attribute__((ext_vector_type(8)));
typedef float float4v __attribute__((ext_vector_type(4)));

// ---------------- CSR build: bucket partition (ebuf packed: src<<8 | dst&255) ----------------

__global__ __launch_bounds__(256) void kb_hist(const int* __restrict__ dst, int* __restrict__ bcount) {
    __shared__ int hist[NBUCK];
    const int t = threadIdx.x;
    for (int b = t; b < NBUCK; b += 256) hist[b] = 0;
    __syncthreads();
    const int e0 = blockIdx.x * PART_TILE;
    #pragma unroll
    for (int k = 0; k < 16; k++) {
        int e = e0 + k * 256 + t;
        if (e < N_EDGES_C) atomicAdd(&hist[dst[e] >> 8], 1);
    }
    __syncthreads();
    for (int b = t; b < NBUCK; b += 256) {
        int c = hist[b];
        if (c) atomicAdd(&bcount[b], c);
    }
}

__global__ __launch_bounds__(512) void kb_scan(const int* __restrict__ bcount,
                                               int* __restrict__ bbase, int* __restrict__ bcursor) {
    __shared__ int s[512];
    const int t = threadIdx.x;
    int v = (t < NBUCK) ? bcount[t] : 0;
    s[t] = v;
    __syncthreads();
    for (int off = 1; off < 512; off <<= 1) {
        int u = (t >= off) ? s[t - off] : 0;
        __syncthreads();
        s[t] += u;
        __syncthreads();
    }
    if (t < NBUCK) { int e = s[t] - v; bbase[t] = e; bcursor[t] = e; }
    if (t == 0) bbase[NBUCK] = N_EDGES_C;
}

__global__ __launch_bounds__(256) void kb_part(const int* __restrict__ src, const int* __restrict__ dst,
                                               int* __restrict__ bcursor, unsigned int* __restrict__ ebuf) {
    __shared__ int hist[NBUCK];
    __shared__ int startA[NBUCK];
    __shared__ int lcur[NBUCK];
    const int t = threadIdx.x;
    for (int b = t; b < NBUCK; b += 256) { hist[b] = 0; lcur[b] = 0; }
    __syncthreads();
    const int e0 = blockIdx.x * PART_TILE;
    #pragma unroll
    for (int k = 0; k < 16; k++) {
        int e = e0 + k * 256 + t;
        if (e < N_EDGES_C) atomicAdd(&hist[dst[e] >> 8], 1);
    }
    __syncthreads();
    for (int b = t; b < NBUCK; b += 256) {
        int c = hist[b];
        startA[b] = c ? atomicAdd(&bcursor[b], c) : 0;
    }
    __syncthreads();
    #pragma unroll
    for (int k = 0; k < 16; k++) {
        int e = e0 + k * 256 + t;
        if (e < N_EDGES_C) {
            int d = dst[e];
            int b = d >> 8;
            int pos = startA[b] + atomicAdd(&lcur[b], 1);
            ebuf[pos] = ((unsigned int)src[e] << 8) | (unsigned int)(d & 255);
        }
    }
}

// One block per bucket: local count+scan -> offs, norm, csr_src (all writes bucket-local).
__global__ __launch_bounds__(256) void kb_fill(const unsigned int* __restrict__ ebuf, const int* __restrict__ bbase,
                                               int* __restrict__ csr_src, int* __restrict__ offs,
                                               float* __restrict__ norm) {
    __shared__ int s[256];
    __shared__ int excl[256];
    __shared__ int lcur[256];
    const int b = blockIdx.x, t = threadIdx.x;
    const int base = b << 8;
    const int e0 = bbase[b], e1 = bbase[b + 1];
    s[t] = 0; lcur[t] = 0;
    __syncthreads();
    for (int e = e0 + t; e < e1; e += 256)
        atomicAdd(&s[ebuf[e] & 255u], 1);
    __syncthreads();
    int own = s[t];
    for (int off = 1; off < 256; off <<= 1) {
        int v = (t >= off) ? s[t - off] : 0;
        __syncthreads();
        s[t] += v;
        __syncthreads();
    }
    excl[t] = s[t] - own;
    int node = base + t;
    if (node < N_NODES_C) {
        offs[node] = e0 + (s[t] - own);
        norm[node] = rsqrtf((float)own + 1.0f);
    }
    if (b == 0 && t == 0) offs[N_NODES_C] = N_EDGES_C;
    __syncthreads();
    for (int e = e0 + t; e < e1; e += 256) {
        unsigned int p = ebuf[e];
        int l = p & 255u;
        int pos = e0 + excl[l] + atomicAdd(&lcur[l], 1);
        csr_src[pos] = (int)(p >> 8);
    }
}

// ---------------- precompute ----------------

// x -> fp16
__global__ __launch_bounds__(256) void k_cast(const float* __restrict__ x, _Float16* __restrict__ xh) {
    long base = ((long)blockIdx.x * 256 + threadIdx.x) * 8;
    float4 a = *(const float4*)&x[base];
    float4 b = *(const float4*)&x[base + 4];
    _Float16 p[8] = {(_Float16)a.x, (_Float16)a.y, (_Float16)a.z, (_Float16)a.w,
                     (_Float16)b.x, (_Float16)b.y, (_Float16)b.z, (_Float16)b.w};
    *(half8*)&xh[base] = *(half8*)p;
}

// W -> fp16 transposed [n][k]
__global__ __launch_bounds__(256) void k_tw(const float* __restrict__ Ws_all, _Float16* __restrict__ WT) {
    int idx = blockIdx.x * 256 + threadIdx.x;     // 4*128*128 = 65536
    int l = idx >> 14, r = idx & 16383, k = r >> 7, n = r & 127;
    WT[l * 16384 + n * HID + k] = (_Float16)Ws_all[idx];
}

// Fold bias+BN into per-channel scale/shift: out = z*A + B
__global__ __launch_bounds__(256) void k_bn(const float* __restrict__ bs, const float* __restrict__ mean,
                                            const float* __restrict__ gamma, const float* __restrict__ var,
                                            const float* __restrict__ beta,
                                            float* __restrict__ Asc, float* __restrict__ Bsh) {
    int i = blockIdx.x * 256 + threadIdx.x;       // 4*128 = 512
    if (i < 4 * HID) {
        float sc = gamma[i] * rsqrtf(var[i] + BN_EPS_C);
        Asc[i] = sc;
        Bsh[i] = (bs[i] - mean[i]) * sc + beta[i];
    }
}

// ---------------- MFMA GEMM: Y[r,:] = norm[r] * (A[r,:] @ W), fp16 in/out, no LDS ----------------
// Operand swap: mfma(A_op=W^T frag, B_op=node rows) -> lane holds 4 consecutive channels.

__global__ __launch_bounds__(256) void k_gemm(const _Float16* __restrict__ Ah,
                                              const _Float16* __restrict__ WT,   // [128 n][128 k] fp16
                                              const float* __restrict__ norm,
                                              _Float16* __restrict__ Y, int nrows) {
    const int tid = threadIdx.x;
    const int wave = tid >> 6, lane = tid & 63, quad = lane >> 4, l16 = lane & 15;

    half8 Wf[2][4];   // this wave's 32 output channels, straight from L2-resident WT
    #pragma unroll
    for (int c = 0; c < 2; c++)
        #pragma unroll
        for (int ks = 0; ks < 4; ks++)
            Wf[c][ks] = *(const half8*)&WT[((wave * 2 + c) * 16 + l16) * HID + ks * 32 + quad * 8];

    const int nbase = blockIdx.x * 128;
    #pragma unroll
    for (int t = 0; t < 8; t++) {
        int node = nbase + t * 16 + l16;
        bool ok = node < nrows;
        half8 Af[4];
        const _Float16* arow = Ah + (long)node * HID;
        #pragma unroll
        for (int ks = 0; ks < 4; ks++)
            Af[ks] = ok ? *(const half8*)&arow[ks * 32 + quad * 8] : half8{};
        float4v a0 = {0.f, 0.f, 0.f, 0.f}, a1 = {0.f, 0.f, 0.f, 0.f};
        #pragma unroll
        for (int ks = 0; ks < 4; ks++) {
            a0 = __builtin_amdgcn_mfma_f32_16x16x32_f16(Wf[0][ks], Af[ks], a0, 0, 0, 0);
            a1 = __builtin_amdgcn_mfma_f32_16x16x32_f16(Wf[1][ks], Af[ks], a1, 0, 0, 0);
        }
        if (ok) {
            float nv = norm[node];
            _Float16 p0[4], p1[4];
            #pragma unroll
            for (int r = 0; r < 4; r++) {
                p0[r] = (_Float16)(a0[r] * nv);
                p1[r] = (_Float16)(a1[r] * nv);
            }
            *(ushort4*)&Y[(long)node * HID + (wave * 2 + 0) * 16 + quad * 4] = *(ushort4*)p0;
            *(ushort4*)&Y[(long)node * HID + (wave * 2 + 1) * 16 + quad * 4] = *(ushort4*)p1;
        }
    }
}

// ---------------- Aggregation + BN(eval fold) + ReLU ----------------
// One wave per node. Quarter-wave per edge: lane (q=lane>>4, cl=lane&15) loads 16B = 8 channels;
// one wave instr gathers 4 edge-rows (1 KB). h_i = ReLU((n_i(Σ y_s + y_i))*Asc + Bsh), fp16 out.

__global__ __launch_bounds__(256) void k_agg(const _Float16* __restrict__ y, const int* __restrict__ offs,
                                             const int* __restrict__ csr_src, const float* __restrict__ norm,
                                             const float* __restrict__ Asc, const float* __restrict__ Bsh,
                                             _Float16* __restrict__ h) {
    const int wave = threadIdx.x >> 6;
    const int lane = threadIdx.x & 63;
    const int q = lane >> 4, cl = lane & 15;
    const int i = blockIdx.x * 4 + wave;         // grid covers exactly N_NODES_C

    float acc[8] = {0.f, 0.f, 0.f, 0.f, 0.f, 0.f, 0.f, 0.f};
    if (q == 0) {   // self term y_i (added once)
        half8 sv = *(const half8*)&y[(long)i * HID + cl * 8];
        #pragma unroll
        for (int r = 0; r < 8; r++) acc[r] += (float)sv[r];
    }

    const int e0 = offs[i], e1 = offs[i + 1];
    int e = e0;
    for (; e + 16 <= e1; e += 16) {      // 4 wave-instrs in flight, 16 edges
        int s0 = csr_src[e + q];
        int s1 = csr_src[e + 4 + q];
        int s2 = csr_src[e + 8 + q];
        int s3 = csr_src[e + 12 + q];
        half8 v0 = *(const half8*)&y[(long)s0 * HID + cl * 8];
        half8 v1 = *(const half8*)&y[(long)s1 * HID + cl * 8];
        half8 v2 = *(const half8*)&y[(long)s2 * HID + cl * 8];
        half8 v3 = *(const half8*)&y[(long)s3 * HID + cl * 8];
        #pragma unroll
        for (int r = 0; r < 8; r++)
            acc[r] += (float)v0[r] + (float)v1[r] + (float)v2[r] + (float)v3[r];
    }
    for (; e + 4 <= e1; e += 4) {
        int s = csr_src[e + q];
        half8 v = *(const half8*)&y[(long)s * HID + cl * 8];
        #pragma unroll
        for (int r = 0; r < 8; r++) acc[r] += (float)v[r];
    }
    if (e + q < e1) {
        int s = csr_src[e + q];
        half8 v = *(const half8*)&y[(long)s * HID + cl * 8];
        #pragma unroll
        for (int r = 0; r < 8; r++) acc[r] += (float)v[r];
    }

    #pragma unroll
    for (int r = 0; r < 8; r++) {
        acc[r] += __shfl_xor(acc[r], 16);
        acc[r] += __shfl_xor(acc[r], 32);
    }

    if (q == 0) {
        float ni = norm[i];
        float4 A0 = *(const float4*)&Asc[cl * 8];
        float4 A1 = *(const float4*)&Asc[cl * 8 + 4];
        float4 B0 = *(const float4*)&Bsh[cl * 8];
        float4 B1 = *(const float4*)&Bsh[cl * 8 + 4];
        _Float16 p[8];
        p[0] = (_Float16)fmaxf(acc[0] * ni * A0.x + B0.x, 0.f);
        p[1] = (_Float16)fmaxf(acc[1] * ni * A0.y + B0.y, 0.f);
        p[2] = (_Float16)fmaxf(acc[2] * ni * A0.z + B0.z, 0.f);
        p[3] = (_Float16)fmaxf(acc[3] * ni * A0.w + B0.w, 0.f);
        p[4] = (_Float16)fmaxf(acc[4] * ni * A1.x + B1.x, 0.f);
        p[5] = (_Float16)fmaxf(acc[5] * ni * A1.y + B1.y, 0.f);
        p[6] = (_Float16)fmaxf(acc[6] * ni * A1.z + B1.z, 0.f);
        p[7] = (_Float16)fmaxf(acc[7] * ni * A1.w + B1.w, 0.f);
        *(half8*)&h[(long)i * HID + cl * 8] = *(half8*)p;
    }
}

// ---------------- Pooling (batch sorted -> run-length local accumulation) ----------------

__global__ __launch_bounds__(64) void k_pool(const __half* __restrict__ h, const int* __restrict__ batch,
                                             float* __restrict__ psum, int* __restrict__ pcount) {
    const int j = threadIdx.x;          // channel pair j -> channels 2j, 2j+1
    const int i0 = blockIdx.x * 128;
    const int iend = min(i0 + 128, N_NODES_C);
    if (i0 >= N_NODES_C) return;
    float acc0 = 0.f, acc1 = 0.f;
    int cur = batch[i0];
    int runStart = i0;
    for (int i = i0; i < iend; i++) {
        int gidx = batch[i];
        if (gidx != cur) {
            atomicAdd(&psum[(long)cur * HID + 2 * j], acc0);
            atomicAdd(&psum[(long)cur * HID + 2 * j + 1], acc1);
            if (j == 0) atomicAdd(&pcount[cur], i - runStart);
            acc0 = 0.f; acc1 = 0.f; cur = gidx; runStart = i;
        }
        float2 f = __half22float2(*(const __half2*)&h[(long)i * HID + 2 * j]);
        acc0 += f.x; acc1 += f.y;
    }
    atomicAdd(&psum[(long)cur * HID + 2 * j], acc0);
    atomicAdd(&psum[(long)cur * HID + 2 * j + 1], acc1);
    if (j == 0) atomicAdd(&pcount[cur], iend - runStart);
}

__global__ __launch_bounds__(128) void k_final(const float* __restrict__ psum, const int* __restrict__ pcount,
                                               const float* __restrict__ W_out, const float* __restrict__ b_out,
                                               float* __restrict__ out) {
    __shared__ float red[128][5];
    const int g = blockIdx.x, j = threadIdx.x;
    float cnt = fmaxf((float)pcount[g], 1.f);
    float p = psum[(long)g * HID + j] / cnt;
    #pragma unroll
    for (int o = 0; o < 5; o++) red[j][o] = p * W_out[j * 5 + o];
    __syncthreads();
    for (int off = 64; off >= 1; off >>= 1) {
        if (j < off) {
            #pragma unroll
            for (int o = 0; o < 5; o++) red[j][o] += red[j + off][o];
        }
        __syncthreads();
    }
    if (j < 5) out[g * 5 + j] = red[0][j] + b_out[j];
}

// ---------------- launch ----------------

extern "C" void kernel_launch(void* const* d_in, const int* in_sizes, int n_in,
                              void* d_out, int out_size, void* d_ws, size_t ws_size,
                              hipStream_t stream) {
    const float* x        = (const float*)d_in[0];
    const int*   eidx     = (const int*)d_in[1];
    const int*   src      = eidx;
    const int*   dst      = eidx + N_EDGES_C;
    const int*   batch    = (const int*)d_in[2];
    const float* Ws_all   = (const float*)d_in[3];
    const float* bs       = (const float*)d_in[4];
    const float* gammas   = (const float*)d_in[5];
    const float* betas    = (const float*)d_in[6];
    const float* run_mean = (const float*)d_in[7];
    const float* run_var  = (const float*)d_in[8];
    const float* W_out    = (const float*)d_in[9];
    const float* b_out    = (const float*)d_in[10];
    float* out = (float*)d_out;

    char* wp = (char*)d_ws;
    auto alloc = [&](size_t bytes) { char* p = wp; wp += (bytes + 255) & ~(size_t)255; return p; };
    _Float16* xh      = (_Float16*)alloc((size_t)N_NODES_C * HID * 2);
    _Float16* y       = (_Float16*)alloc((size_t)N_NODES_C * HID * 2);   // 25.6 MB
    unsigned int* ebuf = (unsigned int*)y;                               // alias: dead before first k_gemm
    _Float16* h       = (_Float16*)alloc((size_t)N_NODES_C * HID * 2);
    _Float16* WT      = (_Float16*)alloc((size_t)4 * HID * HID * 2);
    float*    Asc     = (float*)alloc((size_t)4 * HID * 4);
    float*    Bsh     = (float*)alloc((size_t)4 * HID * 4);
    int*      csr_src = (int*)alloc((size_t)N_EDGES_C * 4);
    int*      offs    = (int*)alloc((size_t)(N_NODES_C + 1) * 4);
    float*    norm    = (float*)alloc((size_t)N_NODES_C * 4);
    int*      bcount  = (int*)alloc((NBUCK + 1) * 4);
    int*      bbase   = (int*)alloc((NBUCK + 1) * 4);
    int*      bcursor = (int*)alloc((NBUCK + 1) * 4);
    float*    psum    = (float*)alloc((size_t)N_GRAPHS_C * HID * 4);
    int*      pcount  = (int*)alloc((size_t)N_GRAPHS_C * 4);

    hipMemsetAsync(bcount, 0, (NBUCK + 1) * 4, stream);
    hipMemsetAsync(psum,   0, (size_t)N_GRAPHS_C * HID * 4, stream);
    hipMemsetAsync(pcount, 0, (size_t)N_GRAPHS_C * 4, stream);

    const int PB = (N_EDGES_C + PART_TILE - 1) / PART_TILE;  // 391
    kb_hist<<<PB, 256, 0, stream>>>(dst, bcount);
    kb_scan<<<1, 512, 0, stream>>>(bcount, bbase, bcursor);
    kb_part<<<PB, 256, 0, stream>>>(src, dst, bcursor, ebuf);
    kb_fill<<<NBUCK, 256, 0, stream>>>(ebuf, bbase, csr_src, offs, norm);

    k_tw  <<<256, 256, 0, stream>>>(Ws_all, WT);
    k_bn  <<<2, 256, 0, stream>>>(bs, run_mean, gammas, run_var, betas, Asc, Bsh);
    k_cast<<<(N_NODES_C * HID) / 2048, 256, 0, stream>>>(x, xh);

    const int GB = (N_NODES_C + 127) / 128;   // 782
    const int AB = (N_NODES_C + 3) / 4;       // 25000
    for (int l = 0; l < 4; l++) {
        const _Float16* A = (l == 0) ? xh : h;
        k_gemm<<<GB, 256, 0, stream>>>(A, WT + (size_t)l * HID * HID, norm, y, N_NODES_C);
        k_agg<<<AB, 256, 0, stream>>>(y, offs, csr_src, norm,
                                      Asc + l * HID, Bsh + l * HID, h);
    }
    k_pool <<<GB, 64, 0, stream>>>((const __half*)h, batch, psum, pcount);
    k_final<<<N_GRAPHS_C, 128, 0, stream>>>(psum, pcount, W_out, b_out, out);
}